// Round 2
// baseline (299.351 us; speedup 1.0000x reference)
//
#include <hip/hip_runtime.h>
#include <math.h>

#define N_NODES 50000
#define IN_CH   128
#define TOT_CH  128          // HEADS*OUT_CH
#define NEDGE   800000
#define ETOT    (NEDGE + N_NODES)
#define NEG_SLOPE 0.2f

// ---------------- workspace layout (bytes) ----------------
#define OFF_XL      ((size_t)0)
#define OFF_XR      ((size_t)25600000)          // N*128*4
#define OFF_ROWPTR  ((size_t)51200000)          // (N+1)*4 -> pad
#define OFF_DEG     ((size_t)51400064)
#define OFF_CURSOR  ((size_t)51600064)
#define OFF_SRC     ((size_t)51800064)          // ETOT*4 = 3.4MB
// total ~55.2 MB

// ================= GEMM: x[N,128] @ [Wl|Wr][128,256] -> xl, xr =================
// block 256 = 4 waves; each wave: 16 rows; lane covers 4 cols of 256 combined.
#define FMA4(a, s, wv4) do { (a).x = fmaf((s),(wv4).x,(a).x); (a).y = fmaf((s),(wv4).y,(a).y); \
                             (a).z = fmaf((s),(wv4).z,(a).z); (a).w = fmaf((s),(wv4).w,(a).w); } while(0)

__global__ __launch_bounds__(256) void gemm_kernel(
    const float* __restrict__ x, const float* __restrict__ Wl,
    const float* __restrict__ Wr, float* __restrict__ xl, float* __restrict__ xr)
{
    const int lane = threadIdx.x & 63;
    const int wv   = threadIdx.x >> 6;
    const int rowbase = __builtin_amdgcn_readfirstlane(blockIdx.x * 64 + wv * 16);
    const float* __restrict__ Wbase = (lane < 32) ? Wl : Wr;
    const int col = (lane & 31) * 4;

    float4 acc[16];
#pragma unroll
    for (int r = 0; r < 16; ++r) acc[r] = make_float4(0.f, 0.f, 0.f, 0.f);

#pragma unroll 2
    for (int d4 = 0; d4 < IN_CH; d4 += 4) {
        const float4 w0 = *(const float4*)(Wbase + (size_t)(d4 + 0) * TOT_CH + col);
        const float4 w1 = *(const float4*)(Wbase + (size_t)(d4 + 1) * TOT_CH + col);
        const float4 w2 = *(const float4*)(Wbase + (size_t)(d4 + 2) * TOT_CH + col);
        const float4 w3 = *(const float4*)(Wbase + (size_t)(d4 + 3) * TOT_CH + col);
#pragma unroll
        for (int r = 0; r < 16; ++r) {
            int row = rowbase + r;
            row = (row < N_NODES) ? row : (N_NODES - 1);
            const float4 xv = *(const float4*)(x + (size_t)row * IN_CH + d4);
            FMA4(acc[r], xv.x, w0);
            FMA4(acc[r], xv.y, w1);
            FMA4(acc[r], xv.z, w2);
            FMA4(acc[r], xv.w, w3);
        }
    }

#pragma unroll
    for (int r = 0; r < 16; ++r) {
        const int row = rowbase + r;
        if (row < N_NODES) {
            float* dst = (lane < 32) ? (xl + (size_t)row * TOT_CH + col)
                                     : (xr + (size_t)row * TOT_CH + col);
            *(float4*)dst = acc[r];
        }
    }
}

// ================= CSR build =================
__global__ void init_deg_kernel(int* __restrict__ deg) {
    int i = blockIdx.x * 256 + threadIdx.x;
    if (i < N_NODES) deg[i] = 1;   // self loop
}

__global__ void hist_kernel(const int* __restrict__ ei, int* __restrict__ deg) {
    int e = blockIdx.x * 256 + threadIdx.x;
    if (e < NEDGE) atomicAdd(&deg[ei[NEDGE + e]], 1);
}

__global__ __launch_bounds__(1024) void scan_kernel(
    const int* __restrict__ deg, int* __restrict__ rowptr, int* __restrict__ cursor)
{
    __shared__ int wsum[16];
    __shared__ int carry;
    const int tid = threadIdx.x, lane = tid & 63, wid = tid >> 6;
    if (tid == 0) { carry = 0; rowptr[0] = 0; }
    __syncthreads();
    for (int base = 0; base < N_NODES; base += 1024) {
        const int i = base + tid;
        const int v = (i < N_NODES) ? deg[i] : 0;
        int s = v;
#pragma unroll
        for (int off = 1; off < 64; off <<= 1) {
            int t = __shfl_up(s, off);
            if (lane >= off) s += t;
        }
        if (lane == 63) wsum[wid] = s;
        __syncthreads();
        if (tid == 0) {
            int acc = carry;
#pragma unroll
            for (int w = 0; w < 16; ++w) { int t = wsum[w]; wsum[w] = acc; acc += t; }
            carry = acc;
        }
        __syncthreads();
        const int excl = wsum[wid] + s - v;
        if (i < N_NODES) { cursor[i] = excl; rowptr[i + 1] = excl + v; }
        __syncthreads();
    }
}

__global__ void scatter_kernel(const int* __restrict__ ei, int* __restrict__ cursor,
                               int* __restrict__ sorted_src) {
    int e = blockIdx.x * 256 + threadIdx.x;
    if (e >= ETOT) return;
    int src, dst;
    if (e < NEDGE) { src = ei[e]; dst = ei[NEDGE + e]; }
    else           { src = dst = e - NEDGE; }
    int pos = atomicAdd(&cursor[dst], 1);
    sorted_src[pos] = src;
}

// ================= fused attention + aggregate: one wave per dst node =========
__global__ __launch_bounds__(256) void gat_kernel(
    const float* __restrict__ xl, const float* __restrict__ xr,
    const int* __restrict__ rowptr, const int* __restrict__ srcs,
    const float* __restrict__ att, const float* __restrict__ bias,
    float* __restrict__ out)
{
    const int lane = threadIdx.x & 63;
    const int i = blockIdx.x * 4 + (threadIdx.x >> 6);
    if (i >= N_NODES) return;
    const int c = lane * 2;                      // 2 channels per lane; head = lane>>4
    const float2 att2 = *(const float2*)(att + c);
    const float2 xr2  = *(const float2*)(xr + (size_t)i * TOT_CH + c);
    const int k0 = rowptr[i], k1 = rowptr[i + 1];

    float m = -INFINITY, den = 0.f, a0 = 0.f, a1 = 0.f;
    for (int k = k0; k < k1; ++k) {
        const int j = srcs[k];
        const float2 xl2 = *(const float2*)(xl + (size_t)j * TOT_CH + c);
        const float t0 = xl2.x + xr2.x, t1 = xl2.y + xr2.y;
        const float l0 = fmaxf(t0, 0.f) + NEG_SLOPE * fminf(t0, 0.f);
        const float l1 = fmaxf(t1, 0.f) + NEG_SLOPE * fminf(t1, 0.f);
        float s = att2.x * l0 + att2.y * l1;
        // reduce over the 16 lanes of this head (xor within aligned 16-group)
        s += __shfl_xor(s, 1);
        s += __shfl_xor(s, 2);
        s += __shfl_xor(s, 4);
        s += __shfl_xor(s, 8);
        const float mn   = fmaxf(m, s);
        const float corr = __expf(m - mn);   // first iter: exp(-inf)=0
        const float p    = __expf(s - mn);
        den = den * corr + p;
        a0  = a0 * corr + p * xl2.x;
        a1  = a1 * corr + p * xl2.y;
        m = mn;
    }
    const float inv = 1.f / den;
    const float2 b2 = *(const float2*)(bias + c);
    float2 o;
    o.x = a0 * inv + b2.x;
    o.y = a1 * inv + b2.y;
    *(float2*)(out + (size_t)i * TOT_CH + c) = o;
}

// ================= launch =================
extern "C" void kernel_launch(void* const* d_in, const int* in_sizes, int n_in,
                              void* d_out, int out_size, void* d_ws, size_t ws_size,
                              hipStream_t stream) {
    const float* x    = (const float*)d_in[0];
    const int*   ei   = (const int*)d_in[1];
    const float* Wl   = (const float*)d_in[2];
    const float* Wr   = (const float*)d_in[3];
    const float* att  = (const float*)d_in[4];
    const float* bias = (const float*)d_in[5];
    float* out = (float*)d_out;
    char*  ws  = (char*)d_ws;

    float* xl     = (float*)(ws + OFF_XL);
    float* xr     = (float*)(ws + OFF_XR);
    int*   rowptr = (int*)(ws + OFF_ROWPTR);
    int*   deg    = (int*)(ws + OFF_DEG);
    int*   cursor = (int*)(ws + OFF_CURSOR);
    int*   ssrc   = (int*)(ws + OFF_SRC);

    hipLaunchKernelGGL(gemm_kernel, dim3((N_NODES + 63) / 64), dim3(256), 0, stream,
                       x, Wl, Wr, xl, xr);
    hipLaunchKernelGGL(init_deg_kernel, dim3((N_NODES + 255) / 256), dim3(256), 0, stream, deg);
    hipLaunchKernelGGL(hist_kernel, dim3((NEDGE + 255) / 256), dim3(256), 0, stream, ei, deg);
    hipLaunchKernelGGL(scan_kernel, dim3(1), dim3(1024), 0, stream, deg, rowptr, cursor);
    hipLaunchKernelGGL(scatter_kernel, dim3((ETOT + 255) / 256), dim3(256), 0, stream,
                       ei, cursor, ssrc);
    hipLaunchKernelGGL(gat_kernel, dim3((N_NODES + 3) / 4), dim3(256), 0, stream,
                       xl, xr, rowptr, ssrc, att, bias, out);
}